// Round 2
// baseline (543.577 us; speedup 1.0000x reference)
//
#include <hip/hip_runtime.h>
#include <hip/hip_bf16.h>

#define N_ 16
#define C_ 256
#define F_ 64
#define T_ 256

// fixpoint quantize: clip(round(x*scale), -128, 127)/scale, round half-to-even
__device__ __forceinline__ float quantq(float x, float scale, float inv_scale) {
    float v = rintf(x * scale);
    v = fminf(fmaxf(v, -128.0f), 127.0f);
    return v * inv_scale;
}

// ---------------------------------------------------------------------------
// Plane kernel: one block per (n,c) plane, thread = one t column.
// FINAL=false: compute aux, accumulate freq-sum, store quantized mean as int8.
// FINAL=true : recompute aux, add y (int8), quant, relu, store fp32 output.
// ---------------------------------------------------------------------------
template<bool FINAL>
__global__ __launch_bounds__(256) void plane_kernel(
    const float* __restrict__ x,
    const float* __restrict__ wf,
    const float* __restrict__ ssn_g,
    const float* __restrict__ ssn_b,
    const float* __restrict__ ssn_mu,
    const float* __restrict__ ssn_va,
    signed char* __restrict__ mean_s8,
    const signed char* __restrict__ y_s8,
    float* __restrict__ out)
{
    const int plane = blockIdx.x;          // n*C + c
    const int c = plane & (C_ - 1);
    const int t = threadIdx.x;

    const float* xp = x + (size_t)plane * (F_ * T_) + t;

    // quantized freq-conv weights (8,7)
    const float w0 = quantq(wf[c * 3 + 0], 128.f, 1.f / 128.f);
    const float w1 = quantq(wf[c * 3 + 1], 128.f, 1.f / 128.f);
    const float w2 = quantq(wf[c * 3 + 2], 128.f, 1.f / 128.f);

    // SSN params for the 4 sub-spectral groups of this channel
    float m[4], b[4];
    #pragma unroll
    for (int g = 0; g < 4; ++g) {
        const int cs = c * 4 + g;
        const float mm = quantq(ssn_g[cs] * rsqrtf(ssn_va[cs] + 1e-5f),
                                128.f, 1.f / 128.f);
        m[g] = mm;
        b[g] = quantq(ssn_b[cs] - ssn_mu[cs] * mm, 16.f, 1.f / 16.f);
    }

    float yv = 0.f;
    if (FINAL) yv = (float)y_s8[plane * T_ + t] * (1.f / 16.f);

    float xm = 0.f;
    float x0 = xp[0];
    float sum = 0.f;

    float* op = FINAL ? (out + (size_t)plane * (F_ * T_) + t) : nullptr;

    #pragma unroll 8
    for (int f = 0; f < F_; ++f) {
        const float xn = (f < F_ - 1) ? xp[(f + 1) * T_] : 0.f;
        float conv = xm * w0 + x0 * w1 + xn * w2;
        float q1 = quantq(conv, 16.f, 1.f / 16.f);
        const int g = f >> 4;
        float aux = quantq(q1 * m[g] + b[g], 16.f, 1.f / 16.f);
        if (FINAL) {
            float o = quantq(aux + yv, 16.f, 1.f / 16.f);
            o = fmaxf(o, 0.f);
            op[f * T_] = o;
        } else {
            sum += aux;
        }
        xm = x0; x0 = xn;
    }

    if (!FINAL) {
        const float mn = quantq(sum * (1.f / 64.f), 16.f, 1.f / 16.f);
        mean_s8[plane * T_ + t] = (signed char)(int)rintf(mn * 16.f);
    }
}

// ---------------------------------------------------------------------------
// Mean-path kernel: temporal conv + bn2 + relu + 1x1 conv, all on (N,C,1,T).
// One block per (n, 16-wide t tile). Phase 1: thread=c builds z into LDS.
// Phase 2: thread=o does the 256-deep dot product.
// ---------------------------------------------------------------------------
#define TT_ 16
__global__ __launch_bounds__(256) void mean_path_kernel(
    const signed char* __restrict__ mean_s8,
    const float* __restrict__ wt,
    const float* __restrict__ g2,
    const float* __restrict__ b2,
    const float* __restrict__ mu2,
    const float* __restrict__ va2,
    const float* __restrict__ w1,
    signed char* __restrict__ y_s8)
{
    const int n = blockIdx.x >> 4;
    const int tt = (blockIdx.x & 15) * TT_;
    const int tid = threadIdx.x;

    __shared__ float z[TT_][C_];   // 16 KiB

    {   // phase 1: c = tid
        const int c = tid;
        const float wq0 = quantq(wt[c * 3 + 0], 128.f, 1.f / 128.f);
        const float wq1 = quantq(wt[c * 3 + 1], 128.f, 1.f / 128.f);
        const float wq2 = quantq(wt[c * 3 + 2], 128.f, 1.f / 128.f);
        const float m2 = quantq(g2[c] * rsqrtf(va2[c] + 1e-5f),
                                128.f, 1.f / 128.f);
        const float bb2 = quantq(b2[c] - mu2[c] * m2, 16.f, 1.f / 16.f);
        const signed char* mp = mean_s8 + (n * C_ + c) * T_;
        #pragma unroll
        for (int j = 0; j < TT_; ++j) {
            const int t = tt + j;
            const float a = (t > 0)       ? (float)mp[t - 1] * (1.f / 16.f) : 0.f;
            const float bmid =              (float)mp[t]     * (1.f / 16.f);
            const float d = (t < T_ - 1)  ? (float)mp[t + 1] * (1.f / 16.f) : 0.f;
            float tc = a * wq0 + bmid * wq1 + d * wq2;
            float v = quantq(tc, 16.f, 1.f / 16.f);
            v = quantq(v * m2 + bb2, 16.f, 1.f / 16.f);
            v = fmaxf(v, 0.f);               // relu; re-quant is identity here
            z[j][c] = v;
        }
    }
    __syncthreads();
    {   // phase 2: o = tid
        const int o = tid;
        float acc[TT_];
        #pragma unroll
        for (int j = 0; j < TT_; ++j) acc[j] = 0.f;
        const float* wrow = w1 + o * C_;
        for (int c = 0; c < C_; ++c) {
            const float wv = quantq(wrow[c], 128.f, 1.f / 128.f);
            #pragma unroll
            for (int j = 0; j < TT_; ++j) acc[j] += z[j][c] * wv;
        }
        signed char* yp = y_s8 + (n * C_ + o) * T_ + tt;
        #pragma unroll
        for (int j = 0; j < TT_; ++j) {
            const float q = quantq(acc[j], 16.f, 1.f / 16.f);
            yp[j] = (signed char)(int)rintf(q * 16.f);
        }
    }
}

extern "C" void kernel_launch(void* const* d_in, const int* in_sizes, int n_in,
                              void* d_out, int out_size, void* d_ws, size_t ws_size,
                              hipStream_t stream) {
    const float* x       = (const float*)d_in[0];
    const float* w_freq  = (const float*)d_in[1];
    const float* ssn_g   = (const float*)d_in[2];
    const float* ssn_b   = (const float*)d_in[3];
    const float* ssn_mu  = (const float*)d_in[4];
    const float* ssn_va  = (const float*)d_in[5];
    const float* w_temp  = (const float*)d_in[6];
    const float* g2      = (const float*)d_in[7];
    const float* b2      = (const float*)d_in[8];
    const float* mu2     = (const float*)d_in[9];
    const float* va2     = (const float*)d_in[10];
    const float* w_1x1   = (const float*)d_in[11];
    float* out = (float*)d_out;

    signed char* mean_s8 = (signed char*)d_ws;                  // N*C*T = 1 MiB
    signed char* y_s8    = mean_s8 + (size_t)N_ * C_ * T_;      // N*C*T = 1 MiB

    dim3 blk(256);
    // 1) aux + freq-mean
    plane_kernel<false><<<dim3(N_ * C_), blk, 0, stream>>>(
        x, w_freq, ssn_g, ssn_b, ssn_mu, ssn_va, mean_s8, nullptr, nullptr);
    // 2) temporal conv + bn2 + relu + 1x1
    mean_path_kernel<<<dim3(N_ * (T_ / TT_)), blk, 0, stream>>>(
        mean_s8, w_temp, g2, b2, mu2, va2, w_1x1, y_s8);
    // 3) recompute aux, add, quant, relu, store
    plane_kernel<true><<<dim3(N_ * C_), blk, 0, stream>>>(
        x, w_freq, ssn_g, ssn_b, ssn_mu, ssn_va, nullptr, y_s8, out);
}

// Round 3
// 534.285 us; speedup vs baseline: 1.0174x; 1.0174x over previous
//
#include <hip/hip_runtime.h>

#define N_ 16
#define C_ 256
#define F_ 64
#define T_ 256

__device__ __forceinline__ float clampf(float v, float lo, float hi) {
    return fminf(fmaxf(v, lo), hi);
}

// integer code k = clip(rint(x*scale), -128, 127), returned as float
__device__ __forceinline__ float qcode(float x, float scale) {
    return clampf(rintf(x * scale), -128.f, 127.f);
}

// ---------------------------------------------------------------------------
// k1: freq dwconv + q + SSN + q -> aux int8 codes; integer freq-sum -> mean int8.
// One wave per (n,c) plane; lane handles 4 consecutive t (float4 loads).
// ---------------------------------------------------------------------------
__global__ __launch_bounds__(256) void aux_mean_kernel(
    const float* __restrict__ x,
    const float* __restrict__ wf,
    const float* __restrict__ ssn_g,
    const float* __restrict__ ssn_b,
    const float* __restrict__ ssn_mu,
    const float* __restrict__ ssn_va,
    signed char* __restrict__ aux_s8,
    signed char* __restrict__ mean_s8)
{
    const int wave = threadIdx.x >> 6;
    const int lane = threadIdx.x & 63;
    const int plane = blockIdx.x * 4 + wave;     // n*C + c
    const int c = plane & (C_ - 1);
    const int t0 = lane * 4;

    const float4* xp = (const float4*)(x + (size_t)plane * (F_ * T_) + t0);
    signed char*  ap = aux_s8 + (size_t)plane * (F_ * T_) + t0;

    const float w0 = qcode(wf[c * 3 + 0], 128.f) * (1.f / 128.f);
    const float w1 = qcode(wf[c * 3 + 1], 128.f) * (1.f / 128.f);
    const float w2 = qcode(wf[c * 3 + 2], 128.f) * (1.f / 128.f);

    float4 xm = {0.f, 0.f, 0.f, 0.f};
    float4 x0 = xp[0];
    int s0 = 0, s1 = 0, s2 = 0, s3 = 0;

    int f = 0;
    for (int g = 0; g < 4; ++g) {
        const int cs = c * 4 + g;
        const float m = qcode(ssn_g[cs] * rsqrtf(ssn_va[cs] + 1e-5f), 128.f) * (1.f / 128.f);
        const float b = qcode(ssn_b[cs] - ssn_mu[cs] * m, 16.f) * (1.f / 16.f);
        #pragma unroll 4
        for (int fi = 0; fi < 16; ++fi, ++f) {
            float4 xn;
            if (f < F_ - 1) xn = xp[(f + 1) * (T_ / 4)];
            else            xn = make_float4(0.f, 0.f, 0.f, 0.f);

            float ka0, ka1, ka2, ka3;
            {
                float conv = xm.x * w0 + x0.x * w1 + xn.x * w2;
                float q1 = qcode(conv, 16.f) * (1.f / 16.f);
                ka0 = qcode(q1 * m + b, 16.f);
            }
            {
                float conv = xm.y * w0 + x0.y * w1 + xn.y * w2;
                float q1 = qcode(conv, 16.f) * (1.f / 16.f);
                ka1 = qcode(q1 * m + b, 16.f);
            }
            {
                float conv = xm.z * w0 + x0.z * w1 + xn.z * w2;
                float q1 = qcode(conv, 16.f) * (1.f / 16.f);
                ka2 = qcode(q1 * m + b, 16.f);
            }
            {
                float conv = xm.w * w0 + x0.w * w1 + xn.w * w2;
                float q1 = qcode(conv, 16.f) * (1.f / 16.f);
                ka3 = qcode(q1 * m + b, 16.f);
            }
            const int i0 = (int)ka0, i1 = (int)ka1, i2 = (int)ka2, i3 = (int)ka3;
            s0 += i0; s1 += i1; s2 += i2; s3 += i3;
            char4 cv;
            cv.x = (signed char)i0; cv.y = (signed char)i1;
            cv.z = (signed char)i2; cv.w = (signed char)i3;
            *(char4*)(ap + f * T_) = cv;

            xm = x0; x0 = xn;
        }
    }

    // mean over F, quantized to (8,4): code = clip(rint(sum_codes/64))
    char4 mv;
    mv.x = (signed char)(int)clampf(rintf((float)s0 * (1.f / 64.f)), -128.f, 127.f);
    mv.y = (signed char)(int)clampf(rintf((float)s1 * (1.f / 64.f)), -128.f, 127.f);
    mv.z = (signed char)(int)clampf(rintf((float)s2 * (1.f / 64.f)), -128.f, 127.f);
    mv.w = (signed char)(int)clampf(rintf((float)s3 * (1.f / 64.f)), -128.f, 127.f);
    *(char4*)(mean_s8 + (size_t)plane * T_ + t0) = mv;
}

// ---------------------------------------------------------------------------
// k2: temporal conv + q + bn2 + q + relu + 1x1 conv + q on the (N,C,1,T) mean.
// One block per (n, 16-wide t tile). Phase 1: thread=c builds z into LDS.
// Phase 2: thread=o does the 256-deep dot product.
// ---------------------------------------------------------------------------
#define TT_ 16
__global__ __launch_bounds__(256) void mean_path_kernel(
    const signed char* __restrict__ mean_s8,
    const float* __restrict__ wt,
    const float* __restrict__ g2,
    const float* __restrict__ b2,
    const float* __restrict__ mu2,
    const float* __restrict__ va2,
    const float* __restrict__ w1,
    signed char* __restrict__ y_s8)
{
    const int n = blockIdx.x >> 4;
    const int tt = (blockIdx.x & 15) * TT_;
    const int tid = threadIdx.x;

    __shared__ float z[TT_][C_];   // 16 KiB

    {   // phase 1: c = tid
        const int c = tid;
        const float wq0 = qcode(wt[c * 3 + 0], 128.f) * (1.f / 128.f);
        const float wq1 = qcode(wt[c * 3 + 1], 128.f) * (1.f / 128.f);
        const float wq2 = qcode(wt[c * 3 + 2], 128.f) * (1.f / 128.f);
        const float m2 = qcode(g2[c] * rsqrtf(va2[c] + 1e-5f), 128.f) * (1.f / 128.f);
        const float bb2 = qcode(b2[c] - mu2[c] * m2, 16.f) * (1.f / 16.f);
        const signed char* mp = mean_s8 + (n * C_ + c) * T_;
        #pragma unroll
        for (int j = 0; j < TT_; ++j) {
            const int t = tt + j;
            const float a    = (t > 0)      ? (float)mp[t - 1] * (1.f / 16.f) : 0.f;
            const float bmid =                (float)mp[t]     * (1.f / 16.f);
            const float d    = (t < T_ - 1) ? (float)mp[t + 1] * (1.f / 16.f) : 0.f;
            float tc = a * wq0 + bmid * wq1 + d * wq2;
            float v = qcode(tc, 16.f) * (1.f / 16.f);
            v = qcode(v * m2 + bb2, 16.f) * (1.f / 16.f);
            v = fmaxf(v, 0.f);               // relu; re-quant is identity here
            z[j][c] = v;
        }
    }
    __syncthreads();
    {   // phase 2: o = tid
        const int o = tid;
        float acc[TT_];
        #pragma unroll
        for (int j = 0; j < TT_; ++j) acc[j] = 0.f;
        const float* wrow = w1 + o * C_;
        for (int c = 0; c < C_; ++c) {
            const float wv = qcode(wrow[c], 128.f) * (1.f / 128.f);
            #pragma unroll
            for (int j = 0; j < TT_; ++j) acc[j] += z[j][c] * wv;
        }
        signed char* yp = y_s8 + (n * C_ + o) * T_ + tt;
        #pragma unroll
        for (int j = 0; j < TT_; ++j) {
            yp[j] = (signed char)(int)qcode(acc[j], 16.f);
        }
    }
}

// ---------------------------------------------------------------------------
// k3: out = relu(quant(aux + y)) = clamp(ka + ky, 0, 127) / 16 -> fp32.
// One wave per plane; lane handles 4 t (char4 in, float4 out).
// ---------------------------------------------------------------------------
__global__ __launch_bounds__(256) void combine_kernel(
    const signed char* __restrict__ aux_s8,
    const signed char* __restrict__ y_s8,
    float* __restrict__ out)
{
    const int wave = threadIdx.x >> 6;
    const int lane = threadIdx.x & 63;
    const int plane = blockIdx.x * 4 + wave;
    const int t0 = lane * 4;

    const char4 yk = *(const char4*)(y_s8 + (size_t)plane * T_ + t0);
    const int y0 = yk.x, y1 = yk.y, y2 = yk.z, y3 = yk.w;

    const char4* ap = (const char4*)(aux_s8 + (size_t)plane * (F_ * T_) + t0);
    float4* op = (float4*)(out + (size_t)plane * (F_ * T_) + t0);

    #pragma unroll 8
    for (int f = 0; f < F_; ++f) {
        const char4 ak = ap[f * (T_ / 4)];
        const int o0 = min(127, max(0, (int)ak.x + y0));
        const int o1 = min(127, max(0, (int)ak.y + y1));
        const int o2 = min(127, max(0, (int)ak.z + y2));
        const int o3 = min(127, max(0, (int)ak.w + y3));
        float4 ov;
        ov.x = (float)o0 * (1.f / 16.f);
        ov.y = (float)o1 * (1.f / 16.f);
        ov.z = (float)o2 * (1.f / 16.f);
        ov.w = (float)o3 * (1.f / 16.f);
        op[f * (T_ / 4)] = ov;
    }
}

extern "C" void kernel_launch(void* const* d_in, const int* in_sizes, int n_in,
                              void* d_out, int out_size, void* d_ws, size_t ws_size,
                              hipStream_t stream) {
    const float* x       = (const float*)d_in[0];
    const float* w_freq  = (const float*)d_in[1];
    const float* ssn_g   = (const float*)d_in[2];
    const float* ssn_b   = (const float*)d_in[3];
    const float* ssn_mu  = (const float*)d_in[4];
    const float* ssn_va  = (const float*)d_in[5];
    const float* w_temp  = (const float*)d_in[6];
    const float* g2      = (const float*)d_in[7];
    const float* b2      = (const float*)d_in[8];
    const float* mu2     = (const float*)d_in[9];
    const float* va2     = (const float*)d_in[10];
    const float* w_1x1   = (const float*)d_in[11];
    float* out = (float*)d_out;

    signed char* aux_s8  = (signed char*)d_ws;                        // 64 MiB
    signed char* mean_s8 = aux_s8 + (size_t)N_ * C_ * F_ * T_;        // 1 MiB
    signed char* y_s8    = mean_s8 + (size_t)N_ * C_ * T_;            // 1 MiB

    dim3 blk(256);
    aux_mean_kernel<<<dim3(N_ * C_ / 4), blk, 0, stream>>>(
        x, w_freq, ssn_g, ssn_b, ssn_mu, ssn_va, aux_s8, mean_s8);
    mean_path_kernel<<<dim3(N_ * (T_ / TT_)), blk, 0, stream>>>(
        mean_s8, w_temp, g2, b2, mu2, va2, w_1x1, y_s8);
    combine_kernel<<<dim3(N_ * C_ / 4), blk, 0, stream>>>(
        aux_s8, y_s8, out);
}

// Round 5
// 526.323 us; speedup vs baseline: 1.0328x; 1.0151x over previous
//
#include <hip/hip_runtime.h>

#define N_ 16
#define C_ 256
#define F_ 64
#define T_ 256

typedef float f32x4 __attribute__((ext_vector_type(4)));

__device__ __forceinline__ float clampf(float v, float lo, float hi) {
    return fminf(fmaxf(v, lo), hi);
}

// integer code k = clip(rint(x*scale), -128, 127), returned as float
__device__ __forceinline__ float qcode(float x, float scale) {
    return clampf(rintf(x * scale), -128.f, 127.f);
}

// ---------------------------------------------------------------------------
// k1: freq dwconv + q + SSN + q -> aux int8 codes; integer freq-sum -> mean int8.
// One wave per (n,c) plane; lane handles 4 consecutive t (float4 loads).
// Quant chain folded into code domain: ka = clamp(rint(q1_code*m + b_code)).
// NOTE: no nontemporal hints — NT bypass races the harness's cached
// restore/poison ops (R4 post-timing divergence).
// ---------------------------------------------------------------------------
__global__ __launch_bounds__(256) void aux_mean_kernel(
    const float* __restrict__ x,
    const float* __restrict__ wf,
    const float* __restrict__ ssn_g,
    const float* __restrict__ ssn_b,
    const float* __restrict__ ssn_mu,
    const float* __restrict__ ssn_va,
    signed char* __restrict__ aux_s8,
    signed char* __restrict__ mean_s8)
{
    const int wave = threadIdx.x >> 6;
    const int lane = threadIdx.x & 63;
    const int plane = blockIdx.x * 4 + wave;     // n*C + c
    const int c = plane & (C_ - 1);
    const int t0 = lane * 4;

    const f32x4* xp = (const f32x4*)(x + (size_t)plane * (F_ * T_) + t0);
    signed char*  ap = aux_s8 + (size_t)plane * (F_ * T_) + t0;

    const float w0 = qcode(wf[c * 3 + 0], 128.f) * (1.f / 128.f);
    const float w1 = qcode(wf[c * 3 + 1], 128.f) * (1.f / 128.f);
    const float w2 = qcode(wf[c * 3 + 2], 128.f) * (1.f / 128.f);

    f32x4 xm; xm.x = 0.f; xm.y = 0.f; xm.z = 0.f; xm.w = 0.f;
    f32x4 x0 = xp[0];
    int s0 = 0, s1 = 0, s2 = 0, s3 = 0;

    int f = 0;
    for (int g = 0; g < 4; ++g) {
        const int cs = c * 4 + g;
        const float m  = qcode(ssn_g[cs] * rsqrtf(ssn_va[cs] + 1e-5f), 128.f) * (1.f / 128.f);
        const float bc = qcode(ssn_b[cs] - ssn_mu[cs] * m, 16.f);   // bias CODE (= b*16)
        #pragma unroll 8
        for (int fi = 0; fi < 16; ++fi, ++f) {
            f32x4 xn;
            if (f < F_ - 1) xn = xp[(f + 1) * (T_ / 4)];
            else            { xn.x = 0.f; xn.y = 0.f; xn.z = 0.f; xn.w = 0.f; }

            float ka0, ka1, ka2, ka3;
            {
                float conv = xm.x * w0 + x0.x * w1 + xn.x * w2;
                float q1c = clampf(rintf(conv * 16.f), -128.f, 127.f);
                ka0 = clampf(rintf(fmaf(q1c, m, bc)), -128.f, 127.f);
            }
            {
                float conv = xm.y * w0 + x0.y * w1 + xn.y * w2;
                float q1c = clampf(rintf(conv * 16.f), -128.f, 127.f);
                ka1 = clampf(rintf(fmaf(q1c, m, bc)), -128.f, 127.f);
            }
            {
                float conv = xm.z * w0 + x0.z * w1 + xn.z * w2;
                float q1c = clampf(rintf(conv * 16.f), -128.f, 127.f);
                ka2 = clampf(rintf(fmaf(q1c, m, bc)), -128.f, 127.f);
            }
            {
                float conv = xm.w * w0 + x0.w * w1 + xn.w * w2;
                float q1c = clampf(rintf(conv * 16.f), -128.f, 127.f);
                ka3 = clampf(rintf(fmaf(q1c, m, bc)), -128.f, 127.f);
            }
            const int i0 = (int)ka0, i1 = (int)ka1, i2 = (int)ka2, i3 = (int)ka3;
            s0 += i0; s1 += i1; s2 += i2; s3 += i3;
            char4 cv;
            cv.x = (signed char)i0; cv.y = (signed char)i1;
            cv.z = (signed char)i2; cv.w = (signed char)i3;
            *(char4*)(ap + f * T_) = cv;

            xm = x0; x0 = xn;
        }
    }

    // mean over F, quantized to (8,4): code = clip(rint(sum_codes/64))
    char4 mv;
    mv.x = (signed char)(int)clampf(rintf((float)s0 * (1.f / 64.f)), -128.f, 127.f);
    mv.y = (signed char)(int)clampf(rintf((float)s1 * (1.f / 64.f)), -128.f, 127.f);
    mv.z = (signed char)(int)clampf(rintf((float)s2 * (1.f / 64.f)), -128.f, 127.f);
    mv.w = (signed char)(int)clampf(rintf((float)s3 * (1.f / 64.f)), -128.f, 127.f);
    *(char4*)(mean_s8 + (size_t)plane * T_ + t0) = mv;
}

// ---------------------------------------------------------------------------
// k2: temporal conv + q + bn2 + q + relu + 1x1 conv + q on the (N,C,1,T) mean.
// z transposed to [C][TT+4] so phase-2 inner reads are broadcast ds_read_b128.
// ---------------------------------------------------------------------------
#define TT_ 16
#define ZP_ (TT_ + 4)
__global__ __launch_bounds__(256) void mean_path_kernel(
    const signed char* __restrict__ mean_s8,
    const float* __restrict__ wt,
    const float* __restrict__ g2,
    const float* __restrict__ b2,
    const float* __restrict__ mu2,
    const float* __restrict__ va2,
    const float* __restrict__ w1,
    signed char* __restrict__ y_s8)
{
    const int n = blockIdx.x >> 4;
    const int tt = (blockIdx.x & 15) * TT_;
    const int tid = threadIdx.x;

    __shared__ float z[C_][ZP_];   // 20 KiB, rows 80B apart (16B aligned)

    {   // phase 1: c = tid
        const int c = tid;
        const float wq0 = qcode(wt[c * 3 + 0], 128.f) * (1.f / 128.f);
        const float wq1 = qcode(wt[c * 3 + 1], 128.f) * (1.f / 128.f);
        const float wq2 = qcode(wt[c * 3 + 2], 128.f) * (1.f / 128.f);
        const float m2 = qcode(g2[c] * rsqrtf(va2[c] + 1e-5f), 128.f) * (1.f / 128.f);
        const float bc2 = qcode(b2[c] - mu2[c] * m2, 16.f);   // bias code
        const signed char* mp = mean_s8 + (n * C_ + c) * T_;
        #pragma unroll
        for (int j = 0; j < TT_; ++j) {
            const int t = tt + j;
            const float a    = (t > 0)      ? (float)mp[t - 1] : 0.f;   // codes
            const float bmid =                (float)mp[t];
            const float d    = (t < T_ - 1) ? (float)mp[t + 1] : 0.f;
            // conv on values = (code/16); q(.,16) code = clamp(rint(conv*16))
            float tcc = a * wq0 + bmid * wq1 + d * wq2;          // = conv*16
            float q1c = clampf(rintf(tcc), -128.f, 127.f);       // code of q(tc)
            float v   = clampf(rintf(fmaf(q1c, m2, bc2)), -128.f, 127.f); // code
            v = fmaxf(v, 0.f);               // relu on codes
            z[c][j] = v * (1.f / 16.f);      // value for the 1x1 dot
        }
    }
    __syncthreads();
    {   // phase 2: o = tid
        const int o = tid;
        float acc[TT_];
        #pragma unroll
        for (int j = 0; j < TT_; ++j) acc[j] = 0.f;
        const float* wrow = w1 + o * C_;
        for (int c = 0; c < C_; ++c) {
            const float wv = qcode(wrow[c], 128.f) * (1.f / 128.f);
            const f32x4 za = *(const f32x4*)&z[c][0];
            const f32x4 zb = *(const f32x4*)&z[c][4];
            const f32x4 zc = *(const f32x4*)&z[c][8];
            const f32x4 zd = *(const f32x4*)&z[c][12];
            acc[0]  += za.x * wv; acc[1]  += za.y * wv; acc[2]  += za.z * wv; acc[3]  += za.w * wv;
            acc[4]  += zb.x * wv; acc[5]  += zb.y * wv; acc[6]  += zb.z * wv; acc[7]  += zb.w * wv;
            acc[8]  += zc.x * wv; acc[9]  += zc.y * wv; acc[10] += zc.z * wv; acc[11] += zc.w * wv;
            acc[12] += zd.x * wv; acc[13] += zd.y * wv; acc[14] += zd.z * wv; acc[15] += zd.w * wv;
        }
        signed char* yp = y_s8 + (n * C_ + o) * T_ + tt;
        #pragma unroll
        for (int j = 0; j < TT_; ++j) {
            yp[j] = (signed char)(int)qcode(acc[j], 16.f);
        }
    }
}

// ---------------------------------------------------------------------------
// k3: out = relu(quant(aux + y)) = clamp(ka + ky, 0, 127) / 16 -> fp32.
// ---------------------------------------------------------------------------
__global__ __launch_bounds__(256) void combine_kernel(
    const signed char* __restrict__ aux_s8,
    const signed char* __restrict__ y_s8,
    float* __restrict__ out)
{
    const int wave = threadIdx.x >> 6;
    const int lane = threadIdx.x & 63;
    const int plane = blockIdx.x * 4 + wave;
    const int t0 = lane * 4;

    const char4 yk = *(const char4*)(y_s8 + (size_t)plane * T_ + t0);
    const int y0 = yk.x, y1 = yk.y, y2 = yk.z, y3 = yk.w;

    const char4* ap = (const char4*)(aux_s8 + (size_t)plane * (F_ * T_) + t0);
    f32x4* op = (f32x4*)(out + (size_t)plane * (F_ * T_) + t0);

    #pragma unroll 8
    for (int f = 0; f < F_; ++f) {
        const char4 ak = ap[f * (T_ / 4)];
        const int o0 = min(127, max(0, (int)ak.x + y0));
        const int o1 = min(127, max(0, (int)ak.y + y1));
        const int o2 = min(127, max(0, (int)ak.z + y2));
        const int o3 = min(127, max(0, (int)ak.w + y3));
        f32x4 ov;
        ov.x = (float)o0 * (1.f / 16.f);
        ov.y = (float)o1 * (1.f / 16.f);
        ov.z = (float)o2 * (1.f / 16.f);
        ov.w = (float)o3 * (1.f / 16.f);
        op[f * (T_ / 4)] = ov;
    }
}

extern "C" void kernel_launch(void* const* d_in, const int* in_sizes, int n_in,
                              void* d_out, int out_size, void* d_ws, size_t ws_size,
                              hipStream_t stream) {
    const float* x       = (const float*)d_in[0];
    const float* w_freq  = (const float*)d_in[1];
    const float* ssn_g   = (const float*)d_in[2];
    const float* ssn_b   = (const float*)d_in[3];
    const float* ssn_mu  = (const float*)d_in[4];
    const float* ssn_va  = (const float*)d_in[5];
    const float* w_temp  = (const float*)d_in[6];
    const float* g2      = (const float*)d_in[7];
    const float* b2      = (const float*)d_in[8];
    const float* mu2     = (const float*)d_in[9];
    const float* va2     = (const float*)d_in[10];
    const float* w_1x1   = (const float*)d_in[11];
    float* out = (float*)d_out;

    signed char* aux_s8  = (signed char*)d_ws;                        // 64 MiB
    signed char* mean_s8 = aux_s8 + (size_t)N_ * C_ * F_ * T_;        // 1 MiB
    signed char* y_s8    = mean_s8 + (size_t)N_ * C_ * T_;            // 1 MiB

    dim3 blk(256);
    aux_mean_kernel<<<dim3(N_ * C_ / 4), blk, 0, stream>>>(
        x, w_freq, ssn_g, ssn_b, ssn_mu, ssn_va, aux_s8, mean_s8);
    mean_path_kernel<<<dim3(N_ * (T_ / TT_)), blk, 0, stream>>>(
        mean_s8, w_temp, g2, b2, mu2, va2, w_1x1, y_s8);
    combine_kernel<<<dim3(N_ * C_ / 4), blk, 0, stream>>>(
        aux_s8, y_s8, out);
}